// Round 1
// baseline (170.450 us; speedup 1.0000x reference)
//
#include <hip/hip_runtime.h>
#include <math.h>

// Problem constants (B=8, N=2048, F=64, O=64), f32 in/out.
#define BB 8
#define NN 2048
#define FF 64
#define OO 64
constexpr float ALPHA = 0.2f;

// ---------------------------------------------------------------------------
// K1: per-row sum of A (+1 for the identity), dInv[row] = 1/sqrt(sum).
// One block per row (B*N = 16384 blocks). Read-only on A so A stays L3-hot.
// ---------------------------------------------------------------------------
__global__ __launch_bounds__(256) void k_rowsum(const float* __restrict__ A,
                                                float* __restrict__ dInv) {
    const int row = blockIdx.x;                 // 0 .. B*N-1
    const float* a = A + (size_t)row * NN;
    const int t = threadIdx.x;

    float4 v0 = *(const float4*)(a + t * 4);
    float4 v1 = *(const float4*)(a + t * 4 + 1024);
    float s = v0.x + v0.y + v0.z + v0.w + v1.x + v1.y + v1.z + v1.w;

    // wave (64-lane) reduce
    #pragma unroll
    for (int off = 32; off > 0; off >>= 1) s += __shfl_down(s, off, 64);

    __shared__ float partial[4];
    const int lane = t & 63, w = t >> 6;
    if (lane == 0) partial[w] = s;
    __syncthreads();
    if (t == 0) {
        float tot = partial[0] + partial[1] + partial[2] + partial[3] + 1.0f;
        dInv[row] = 1.0f / sqrtf(tot);
    }
}

// ---------------------------------------------------------------------------
// K2: Y[row, o] = dInv[row] * sum_f X[row, f] * W[f, o]   (row = b*N+n)
// 16 rows per block, 1024 blocks. Tiny (67 MFLOP total).
// ---------------------------------------------------------------------------
__global__ __launch_bounds__(256) void k_xw(const float* __restrict__ X,
                                            const float* __restrict__ W,
                                            const float* __restrict__ dInv,
                                            float* __restrict__ Y) {
    __shared__ float Ws[FF][OO];   // 16 KB
    __shared__ float Xs[16][FF];   // 4 KB
    const int t = threadIdx.x;
    const int r0 = blockIdx.x * 16;

    #pragma unroll
    for (int j = 0; j < 4; ++j) {
        int f4 = t + 256 * j;                       // 0..1023 float4s of W
        ((float4*)Ws)[f4] = ((const float4*)W)[f4];
    }
    ((float4*)Xs)[t] = ((const float4*)(X + (size_t)r0 * FF))[t];
    __syncthreads();

    const int c = t & 63, g = t >> 6;
    float acc[4] = {0.f, 0.f, 0.f, 0.f};
    for (int f = 0; f < FF; ++f) {
        float wv = Ws[f][c];
        #pragma unroll
        for (int i = 0; i < 4; ++i) acc[i] += Xs[g * 4 + i][f] * wv;
    }
    #pragma unroll
    for (int i = 0; i < 4; ++i) {
        int row = r0 + g * 4 + i;
        Y[(size_t)row * OO + c] = dInv[row] * acc[i];
    }
}

// ---------------------------------------------------------------------------
// K3: out0[b,n,o] = leaky( dInv[n] * (sum_m A[b,n,m]*Y[b,m,o] + Y[b,n,o]) + bias[o] )
//     out1 = copy of A (fused into the A-tile staging loads).
// Tile: 32 rows x 64 cols per block, K-chunk 64. 8*64 = 512 blocks, 256 thr.
// Thread (o = t&63, g = t>>6) owns 8 rows (g*8..g*8+7) x 1 col.
// A-tile LDS reads are wave-uniform (broadcast); Y reads are stride-1.
// ---------------------------------------------------------------------------
__global__ __launch_bounds__(256) void k_main(const float* __restrict__ A,
                                              const float* __restrict__ Y,
                                              const float* __restrict__ dInv,
                                              const float* __restrict__ bias,
                                              float* __restrict__ out0,
                                              float* __restrict__ outA) {
    __shared__ float As[32][64];   // 8 KB
    __shared__ float Ys[64][64];   // 16 KB

    const int bx = blockIdx.x;
    const int b  = bx >> 6;                 // 64 row-tiles per batch
    const int n0 = (bx & 63) * 32;
    const float* Ab = A    + ((size_t)b * NN + n0) * NN;
    float*       Cb = outA + ((size_t)b * NN + n0) * NN;
    const float* Yb = Y + (size_t)b * NN * OO;

    const int t = threadIdx.x;
    const int o = t & 63, g = t >> 6;

    float acc[8] = {0.f, 0.f, 0.f, 0.f, 0.f, 0.f, 0.f, 0.f};

    for (int m0 = 0; m0 < NN; m0 += 64) {
        // stage A tile (32x64 f32 = 512 float4s; 2 per thread) + fused copy-out
        #pragma unroll
        for (int j = 0; j < 2; ++j) {
            int f4 = t + 256 * j;
            int r  = f4 >> 4;
            int c4 = (f4 & 15) * 4;
            float4 v = *(const float4*)(Ab + (size_t)r * NN + m0 + c4);
            *(float4*)(Cb + (size_t)r * NN + m0 + c4) = v;
            *(float4*)(&As[r][c4]) = v;
        }
        // stage Y tile (64x64 f32 = 1024 float4s; 4 per thread)
        const float4* Yg = (const float4*)(Yb + (size_t)m0 * OO);
        #pragma unroll
        for (int j = 0; j < 4; ++j) {
            int f4 = t + 256 * j;
            ((float4*)Ys)[f4] = Yg[f4];
        }
        __syncthreads();

        #pragma unroll 8
        for (int mm = 0; mm < 64; mm += 4) {
            float y0 = Ys[mm + 0][o];
            float y1 = Ys[mm + 1][o];
            float y2 = Ys[mm + 2][o];
            float y3 = Ys[mm + 3][o];
            #pragma unroll
            for (int i = 0; i < 8; ++i) {
                float4 a4 = *(const float4*)(&As[g * 8 + i][mm]);
                acc[i] += a4.x * y0;
                acc[i] += a4.y * y1;
                acc[i] += a4.z * y2;
                acc[i] += a4.w * y3;
            }
        }
        __syncthreads();
    }

    const float bv = bias[o];
    #pragma unroll
    for (int i = 0; i < 8; ++i) {
        int row = n0 + g * 8 + i;
        float self = Yb[(size_t)row * OO + o];
        float v = dInv[(size_t)b * NN + row] * (acc[i] + self) + bv;
        out0[((size_t)b * NN + row) * OO + o] = (v >= 0.f) ? v : ALPHA * v;
    }
}

// ---------------------------------------------------------------------------
extern "C" void kernel_launch(void* const* d_in, const int* in_sizes, int n_in,
                              void* d_out, int out_size, void* d_ws, size_t ws_size,
                              hipStream_t stream) {
    const float* X    = (const float*)d_in[0];
    const float* A    = (const float*)d_in[1];
    const float* W    = (const float*)d_in[2];
    const float* bias = (const float*)d_in[3];

    float* out0 = (float*)d_out;                       // [B,N,O]
    float* outA = out0 + (size_t)BB * NN * OO;         // [B,N,N]

    float* dInv = (float*)d_ws;                        // B*N floats (64 KB)
    float* Y    = dInv + (size_t)BB * NN;              // B*N*O floats (4 MB)

    k_rowsum<<<BB * NN, 256, 0, stream>>>(A, dInv);
    k_xw    <<<BB * NN / 16, 256, 0, stream>>>(X, W, dInv, Y);
    k_main  <<<BB * 64, 256, 0, stream>>>(A, Y, dInv, bias, out0, outA);
}

// Round 2
// 89.542 us; speedup vs baseline: 1.9036x; 1.9036x over previous
//
#include <hip/hip_runtime.h>
#include <math.h>

// Problem constants (B=8, N=2048, F=64, O=64), f32 in/out.
#define BB 8
#define NN 2048
#define FF 64
#define OO 64
constexpr float ALPHA = 0.2f;

typedef float  f32x4  __attribute__((ext_vector_type(4)));
typedef short  s16x8  __attribute__((ext_vector_type(8)));
typedef unsigned int u32x4 __attribute__((ext_vector_type(4)));

// round-to-nearest-even f32 -> bf16, two at a time packed into a u32
static __device__ __forceinline__ unsigned int packbf2(float a, float b) {
    unsigned int ua = __builtin_bit_cast(unsigned int, a);
    unsigned int ub = __builtin_bit_cast(unsigned int, b);
    ua = (ua + 0x7FFFu + ((ua >> 16) & 1u)) >> 16;
    ub = (ub + 0x7FFFu + ((ub >> 16) & 1u)) & 0xFFFF0000u;
    return ua | ub;
}

// ---------------------------------------------------------------------------
// K1: dInv[row] = 1/sqrt(1 + sum_m A[row,m]).  One block per row.
// ---------------------------------------------------------------------------
__global__ __launch_bounds__(256) void k_rowsum(const float* __restrict__ A,
                                                float* __restrict__ dInv) {
    const int row = blockIdx.x;
    const float* a = A + (size_t)row * NN;
    const int t = threadIdx.x;

    float4 v0 = *(const float4*)(a + t * 4);
    float4 v1 = *(const float4*)(a + t * 4 + 1024);
    float s = v0.x + v0.y + v0.z + v0.w + v1.x + v1.y + v1.z + v1.w;

    #pragma unroll
    for (int off = 32; off > 0; off >>= 1) s += __shfl_down(s, off, 64);

    __shared__ float partial[4];
    const int lane = t & 63, w = t >> 6;
    if (lane == 0) partial[w] = s;
    __syncthreads();
    if (t == 0) {
        float tot = partial[0] + partial[1] + partial[2] + partial[3] + 1.0f;
        dInv[row] = 1.0f / sqrtf(tot);
    }
}

// ---------------------------------------------------------------------------
// K2: Y[row,o] = dInv[row] * sum_f X[row,f] * W[f,o]
//     writes Yf   [b][n][o]  f32   (for the self-term / epilogue)
//     writes Ytb  [b][o][m]  bf16  (transposed, MFMA B-operand staging source)
// ---------------------------------------------------------------------------
__global__ __launch_bounds__(256) void k_xw(const float* __restrict__ X,
                                            const float* __restrict__ W,
                                            const float* __restrict__ dInv,
                                            float* __restrict__ Yf,
                                            ushort* __restrict__ Ytb) {
    __shared__ float Ws[FF][OO];   // 16 KB
    __shared__ float Xs[16][FF];   // 4 KB
    const int t = threadIdx.x;
    const int r0 = blockIdx.x * 16;

    #pragma unroll
    for (int j = 0; j < 4; ++j) {
        int f4 = t + 256 * j;
        ((float4*)Ws)[f4] = ((const float4*)W)[f4];
    }
    ((float4*)Xs)[t] = ((const float4*)(X + (size_t)r0 * FF))[t];
    __syncthreads();

    const int c = t & 63, g = t >> 6;
    float acc[4] = {0.f, 0.f, 0.f, 0.f};
    for (int f = 0; f < FF; ++f) {
        float wv = Ws[f][c];
        #pragma unroll
        for (int i = 0; i < 4; ++i) acc[i] += Xs[g * 4 + i][f] * wv;
    }
    float y[4];
    #pragma unroll
    for (int i = 0; i < 4; ++i) {
        int row = r0 + g * 4 + i;
        y[i] = dInv[row] * acc[i];
        Yf[(size_t)row * OO + c] = y[i];
    }
    // transposed bf16 copy: Ytb[b][c][n0 + g*4 .. +3]
    const int b = r0 >> 11;           // 2048 rows per batch
    const int n = (r0 & (NN - 1)) + g * 4;
    unsigned int p0 = packbf2(y[0], y[1]);
    unsigned int p1 = packbf2(y[2], y[3]);
    *(uint2*)(Ytb + ((size_t)b * OO + c) * NN + n) = make_uint2(p0, p1);
}

// ---------------------------------------------------------------------------
// K3 (MFMA): out0[b,n,o] = leaky( dInv[n]*(sum_m A[n,m]*Y[m,o] + Y[n,o]) + bias[o] )
//            outA = copy of A (fused with A staging loads).
// Tile: 32 rows x 64 cols, K-chunk 64. 512 blocks, 256 threads (4 waves).
// Wave w: rows (w&1)*16..+15, cols (w>>1)*32..+31 (two 16-col fragments).
// LDS rows padded to 72 bf16 (144 B = 9*16 B): b128-aligned, ~2-way banks.
// ---------------------------------------------------------------------------
__global__ __launch_bounds__(256) void k_main(const float* __restrict__ A,
                                              const ushort* __restrict__ Ytb,
                                              const float* __restrict__ Yf,
                                              const float* __restrict__ dInv,
                                              const float* __restrict__ bias,
                                              float* __restrict__ out0,
                                              float* __restrict__ outA) {
    __shared__ ushort As[32][72];   // 4.5 KB (A tile, bf16)
    __shared__ ushort Ys[64][72];   // 9 KB  (Y^T tile: [o][m], bf16)

    const int bx = blockIdx.x;
    const int b  = bx >> 6;
    const int n0 = (bx & 63) * 32;
    const float*  Ab    = A    + ((size_t)b * NN + n0) * NN;
    float*        Cb    = outA + ((size_t)b * NN + n0) * NN;
    const ushort* Ytb_b = Ytb  + (size_t)b * OO * NN;
    const float*  Yf_b  = Yf   + (size_t)b * NN * OO;
    float*        O_b   = out0 + (size_t)b * NN * OO;

    const int t = threadIdx.x;
    // A staging coords: 32 rows x 64 f32; thread -> 32B contiguous
    const int row_a = t >> 3, ca = (t & 7) * 8;
    // Y staging coords: 64 rows (o) x 64 bf16; thread -> 32B contiguous
    const int row_y = t >> 2, cy = (t & 3) * 16;

    const float*  aSrc = Ab + (size_t)row_a * NN + ca;
    float*        aDst = Cb + (size_t)row_a * NN + ca;
    const ushort* ySrc = Ytb_b + (size_t)row_y * NN + cy;

    const int lane = t & 63, w = t >> 6;
    const int wr = (w & 1) * 16, wc = (w >> 1) * 32;
    const int fr = lane & 15, fg = lane >> 4;

    f32x4 acc0 = {0.f, 0.f, 0.f, 0.f};
    f32x4 acc1 = {0.f, 0.f, 0.f, 0.f};

    float4 pa0, pa1, py0, py1;
    // prefetch first tile
    pa0 = *(const float4*)(aSrc);
    pa1 = *(const float4*)(aSrc + 4);
    py0 = *(const float4*)(ySrc);
    py1 = *(const float4*)(ySrc + 8);

    for (int m0 = 0; m0 < NN; m0 += 64) {
        __syncthreads();   // previous MFMA phase done reading LDS (+ drains loads)
        // fused copy-out of A
        *(float4*)(aDst + m0)     = pa0;
        *(float4*)(aDst + m0 + 4) = pa1;
        // A tile: f32 -> bf16, one b128 LDS write
        u32x4 qa;
        qa.x = packbf2(pa0.x, pa0.y);
        qa.y = packbf2(pa0.z, pa0.w);
        qa.z = packbf2(pa1.x, pa1.y);
        qa.w = packbf2(pa1.z, pa1.w);
        *(u32x4*)&As[row_a][ca] = qa;
        // Y^T tile: already bf16, straight b128 writes
        *(float4*)&Ys[row_y][cy]     = py0;
        *(float4*)&Ys[row_y][cy + 8] = py1;
        __syncthreads();

        if (m0 + 64 < NN) {   // issue next-tile loads; drained at next barrier
            pa0 = *(const float4*)(aSrc + m0 + 64);
            pa1 = *(const float4*)(aSrc + m0 + 68);
            py0 = *(const float4*)(ySrc + m0 + 64);
            py1 = *(const float4*)(ySrc + m0 + 72);
        }

        // MFMA phase: 2 K-substeps of 32
        #pragma unroll
        for (int ks = 0; ks < 2; ++ks) {
            s16x8 af = *(const s16x8*)&As[wr + fr][ks * 32 + fg * 8];
            s16x8 b0 = *(const s16x8*)&Ys[wc + fr][ks * 32 + fg * 8];
            s16x8 b1 = *(const s16x8*)&Ys[wc + 16 + fr][ks * 32 + fg * 8];
            acc0 = __builtin_amdgcn_mfma_f32_16x16x32_bf16(af, b0, acc0, 0, 0, 0);
            acc1 = __builtin_amdgcn_mfma_f32_16x16x32_bf16(af, b1, acc1, 0, 0, 0);
        }
    }

    // epilogue: D lane map (verified): col = lane&15, row = (lane>>4)*4 + reg
    const float bv0 = bias[wc + fr];
    const float bv1 = bias[wc + 16 + fr];
    #pragma unroll
    for (int r = 0; r < 4; ++r) {
        const int nrow = n0 + wr + fg * 4 + r;
        const float di = dInv[(size_t)b * NN + nrow];
        {
            const int col = wc + fr;
            float v = di * (acc0[r] + Yf_b[(size_t)nrow * OO + col]) + bv0;
            O_b[(size_t)nrow * OO + col] = (v >= 0.f) ? v : ALPHA * v;
        }
        {
            const int col = wc + 16 + fr;
            float v = di * (acc1[r] + Yf_b[(size_t)nrow * OO + col]) + bv1;
            O_b[(size_t)nrow * OO + col] = (v >= 0.f) ? v : ALPHA * v;
        }
    }
}

// ---------------------------------------------------------------------------
extern "C" void kernel_launch(void* const* d_in, const int* in_sizes, int n_in,
                              void* d_out, int out_size, void* d_ws, size_t ws_size,
                              hipStream_t stream) {
    const float* X    = (const float*)d_in[0];
    const float* A    = (const float*)d_in[1];
    const float* W    = (const float*)d_in[2];
    const float* bias = (const float*)d_in[3];

    float* out0 = (float*)d_out;                       // [B,N,O]
    float* outA = out0 + (size_t)BB * NN * OO;         // [B,N,N]

    float*  dInv = (float*)d_ws;                       // 16384 f32 (64 KB)
    float*  Yf   = dInv + (size_t)BB * NN;             // 8*2048*64 f32 (4 MB)
    ushort* Ytb  = (ushort*)(Yf + (size_t)BB * NN * OO); // 8*64*2048 bf16 (2 MB)

    k_rowsum<<<BB * NN, 256, 0, stream>>>(A, dInv);
    k_xw    <<<BB * NN / 16, 256, 0, stream>>>(X, W, dInv, Yf, Ytb);
    k_main  <<<BB * 64, 256, 0, stream>>>(A, Ytb, Yf, dInv, bias, out0, outA);
}